// Round 8
// baseline (235.273 us; speedup 1.0000x reference)
//
#include <hip/hip_runtime.h>
#include <hip/hip_bf16.h>

#define NIMG 4

typedef __attribute__((ext_vector_type(8))) _Float16 half8v;
typedef __attribute__((ext_vector_type(2))) _Float16 half2v;
typedef __attribute__((ext_vector_type(4))) float float4v;
typedef __attribute__((ext_vector_type(4))) int   int4v;

__device__ __forceinline__ float sigm(float x){ return 1.f/(1.f+__expf(-x)); }
__device__ __forceinline__ float silu(float x){ return x/(1.f+__expf(-x)); }
__device__ __forceinline__ float lrelu(float x){ return fmaxf(x, 0.01f*x); }

// DPP rotate-add within a 16-lane row (ctrl immediate via template)
template<int CTRL>
__device__ __forceinline__ float dpp_radd(float v){
  int s = __builtin_amdgcn_update_dpp(0, __builtin_bit_cast(int, v), CTRL, 0xF, 0xF, true);
  return v + __builtin_bit_cast(float, s);
}
__device__ __forceinline__ float row16_reduce(float v){
  v = dpp_radd<0x128>(v);  // row_ror:8
  v = dpp_radd<0x124>(v);  // row_ror:4
  v = dpp_radd<0x122>(v);  // row_ror:2
  v = dpp_radd<0x121>(v);  // row_ror:1
  return v;
}

// scale fp16x8 fragment by 4 packed-half2 factors: 4x v_pk_mul_f16
__device__ __forceinline__ half8v scale_frag16(half8v a, const int* tpk){
  int4v ai = __builtin_bit_cast(int4v, a);
  int4v oi;
  #pragma unroll
  for(int p=0;p<4;p++){
    int r;
    asm("v_pk_mul_f16 %0, %1, %2" : "=v"(r) : "v"(ai[p]), "v"(tpk[p]));
    oi[p] = r;
  }
  return __builtin_bit_cast(half8v, oi);
}

// ---------- windowed-sum device helper ----------
template<int DIM, int ODIM>
__device__ void wsum_body(const float* __restrict__ x, float* __restrict__ S,
                          int vb, float* sh){
  const float* xp = x + (size_t)vb*(DIM*DIM*DIM);
  for(int p=threadIdx.x; p<DIM*DIM*DIM; p+=256) sh[p] = silu(xp[p]);
  __syncthreads();
  const int wave = threadIdx.x>>6, lane = threadIdx.x&63;
  for(int tap=wave; tap<27; tap+=4){
    const int kd=tap/9, kh=(tap/3)%3, kw=tap%3;
    const int base = kd*DIM*DIM + kh*DIM + kw;
    float ps = 0.f;
    for(int idx=lane; idx<ODIM*ODIM*ODIM; idx+=64){
      int od = idx/(ODIM*ODIM); int r = idx - od*(ODIM*ODIM);
      int oh = r/ODIM; int ow = r - oh*ODIM;
      ps += sh[base + od*DIM*DIM + oh*DIM + ow];
    }
    #pragma unroll
    for(int m=32;m>=1;m>>=1) ps += __shfl_xor(ps,m);
    if(lane==0) S[vb*27 + tap] = ps;
  }
}

// ---------- K_pre: fused preprocessing (tok | wsum1 | wsum0 | atoms | wt) ----------
__global__ __launch_bounds__(256) void k_pre(
    const float* __restrict__ tf, const float* __restrict__ Wtok,
    const float* __restrict__ btok, float* __restrict__ tok,
    const float* __restrict__ ms1, float* __restrict__ S1,
    const float* __restrict__ ms0, float* __restrict__ S0,
    const float* __restrict__ la, const float* __restrict__ Wa,
    const float* __restrict__ ba, unsigned short* __restrict__ atoms_h,
    float* __restrict__ atom_e,
    const float* __restrict__ Wint, unsigned short* __restrict__ Wt){
  __shared__ float sh[4096];
  const int b = blockIdx.x;
  const int tid = threadIdx.x;
  if(b < 512){
    // ---- tok ----
    const int row = b;
    sh[tid] = silu(tf[row*256 + tid]);
    __syncthreads();
    const int c = tid & 127, sg = tid >> 7;
    float acc = 0.f;
    #pragma unroll 8
    for(int q=sg*128; q<sg*128+128; q++) acc = fmaf(sh[q], Wtok[q*128+c], acc);
    if(sg==1) sh[256+c] = acc;
    __syncthreads();
    if(sg==0) tok[row*128+c] = acc + sh[256+c] + btok[c];
  } else if(b < 768){
    wsum_body<8,6>(ms1, S1, b-512, sh);
  } else if(b < 896){
    wsum_body<16,14>(ms0, S0, b-768, sh);
  } else if(b < 2944){
    // ---- atoms (fp16): 2 rows per block ----
    const int rowb = (b-896)*2;
    if(tid < 128) sh[tid] = la[(size_t)rowb*64 + tid];
    __syncthreads();
    const int r2 = tid>>7, c = tid&127;
    const float* s = sh + r2*64;
    float acc = ba[c];
    #pragma unroll 8
    for(int k=0;k<64;k++) acc = fmaf(s[k], Wa[k*128+c], acc);
    atoms_h[(size_t)(rowb+r2)*128 + c] = __builtin_bit_cast(unsigned short, (_Float16)acc);
    if(tid<2) atom_e[rowb+tid] = 0.f;
  } else {
    // ---- Wt[c][k] = fp16(Wint[k][c]) ----
    const int idx = (b-2944)*256 + tid;
    const int c = idx >> 7, k = idx & 127;
    Wt[c*128 + k] = __builtin_bit_cast(unsigned short, (_Float16)(Wint[k*128 + c]));
  }
}

// ---------- K_pconv: per-(n,c) conv dots + toksum ----------
__global__ void k_pconv(const float* __restrict__ S1, const float* __restrict__ S0,
                        const float* __restrict__ Wc0, const float* __restrict__ bc0,
                        const float* __restrict__ Wc1, const float* __restrict__ bc1,
                        const float* __restrict__ tok, float* __restrict__ toksum,
                        float* __restrict__ pp){
  const int b = blockIdx.x;        // n*128 + c
  const int n = b >> 7, c = b & 127;
  const int tid = threadIdx.x;     // 0..255
  float a0 = 0.f, a1 = 0.f, ts = 0.f;
  { const float* w = Wc0 + c*1728; const float* s = S1 + n*1728;
    for(int q=tid; q<1728; q+=256) a0 = fmaf(w[q], s[q], a0); }
  { const float* w = Wc1 + c*864;  const float* s = S0 + n*864;
    for(int q=tid; q<864; q+=256)  a1 = fmaf(w[q], s[q], a1); }
  for(int j=tid; j<128; j+=256) ts = tok[(n*128+j)*128 + c];
  #pragma unroll
  for(int m=32;m>=1;m>>=1){
    a0 += __shfl_xor(a0,m); a1 += __shfl_xor(a1,m); ts += __shfl_xor(ts,m);
  }
  __shared__ float r0[4], r1[4], r2[4];
  if((tid&63)==0){ r0[tid>>6]=a0; r1[tid>>6]=a1; r2[tid>>6]=ts; }
  __syncthreads();
  if(tid==0){
    float p0 = bc0[c] + (r0[0]+r0[1]+r0[2]+r0[3])*(1.f/216.f);
    float p1 = bc1[c] + (r1[0]+r1[1]+r1[2]+r1[3])*(1.f/2744.f);
    pp[n*256 + c]       = silu(p0);
    pp[n*256 + 128 + c] = silu(p1);
    toksum[n*128 + c]   = r2[0]+r2[1]+r2[2]+r2[3];
  }
}

// ---------- K_pf2: pocket + cat/gate -> pf[n,c] ----------
__global__ void k_pf2(const float* __restrict__ pp, const float* __restrict__ toksum,
                      const float* __restrict__ Wp,  const float* __restrict__ bp,
                      const float* __restrict__ Wcat, const float* __restrict__ bcat,
                      const float* __restrict__ Wgate,const float* __restrict__ bgate,
                      float* __restrict__ pf){
  __shared__ float ps[256];
  __shared__ float zz[384];
  __shared__ float part[4][128];
  __shared__ float partg[4][128];
  const int n = blockIdx.x;
  const int tid = threadIdx.x;     // 0..511
  const int c = tid & 127, s = tid >> 7;
  if(tid < 256) ps[tid] = pp[n*256 + tid];
  __syncthreads();
  float a = 0.f;
  for(int q=s*64; q<s*64+64; q++) a = fmaf(ps[q], Wp[q*128+c], a);
  part[s][c] = a;
  __syncthreads();
  if(s==0){
    float pk = bp[c] + part[0][c]+part[1][c]+part[2][c]+part[3][c];
    float ts = toksum[n*128+c];
    zz[c] = pk; zz[128+c] = ts; zz[256+c] = ts*(1.f/128.f);
  }
  __syncthreads();
  float a1=0.f, a2=0.f;
  for(int q=s*96; q<s*96+96; q++){
    float z = zz[q];
    a1 = fmaf(z, Wcat[q*128+c], a1);
    a2 = fmaf(z, Wgate[q*128+c], a2);
  }
  part[s][c]=a1; partg[s][c]=a2;
  __syncthreads();
  if(s==0){
    float v1 = bcat[c] +part[0][c]+part[1][c]+part[2][c]+part[3][c];
    float v2 = bgate[c]+partg[0][c]+partg[1][c]+partg[2][c]+partg[3][c];
    pf[n*128+c] = v1 * sigm(v2);
  }
}

// ---------- K_inter: fp16 MFMA, barrier-free j-loop, single end combine ----------
// 256 thr = 4 waves. Wave w: atom group g=w>>1 (32 atoms), c-half wc=w&1 (64 c).
// Block: 64 atoms x 8 j. Grid: 1024 (all resident). No per-j barriers: per-j
// d1/d2 partials land in disjoint red[j][g][wc] slots; ONE syncthreads, then a
// 64-thread tail does sigm-combine + one atomicAdd per atom.
__global__ __launch_bounds__(256,2) void k_inter(
    const unsigned short* __restrict__ atoms_h,   // [4096][128] fp16
    const float* __restrict__ tok,                // [512][128] f32
    const unsigned short* __restrict__ Wt,        // [128 c][128 k] fp16
    const float* __restrict__ bint,
    const float* __restrict__ Wpe, const float* __restrict__ bpe,
    const float* __restrict__ Wpg, const float* __restrict__ bpg,
    float* __restrict__ atom_e){
  __shared__ float red[8][2][2][32][2];           // [j][g][wc][atom][d] = 8KB

  const int b0 = blockIdx.x;
  const int bid = (b0 & 7)*128 + (b0 >> 3);       // XCD swizzle (1024%8==0)
  const int n = bid >> 8;
  const int chunk = (bid >> 4) & 15;
  const int jg = bid & 15;                        // j base = jg*8
  const int tid = threadIdx.x;
  const int w = tid >> 6, lane = tid & 63;
  const int t = lane & 15, q = lane >> 4;
  const int g = w >> 1, wc = w & 1;

  const int rbase = n*1024 + chunk*64;

  // ---- A fragments (fp16, unscaled): row = rbase+g*32+fr*16+t, k = ks*32+q*8 ----
  half8v areg[2][4];
  { const unsigned short* ab = atoms_h + (size_t)(rbase + g*32 + t)*128 + q*8;
    #pragma unroll
    for(int fr=0;fr<2;fr++)
      #pragma unroll
      for(int ks=0;ks<4;ks++)
        areg[fr][ks] = *(const half8v*)(ab + fr*16*128 + ks*32);
  }
  // ---- B fragments (W^T fp16, j-invariant): c = wc*64+fc*16+t ----
  half8v breg[4][4];
  { const unsigned short* wb = Wt + (size_t)(wc*64 + t)*128 + q*8;
    #pragma unroll
    for(int fc=0;fc<4;fc++)
      #pragma unroll
      for(int ks=0;ks<4;ks++)
        breg[fc][ks] = *(const half8v*)(wb + fc*16*128 + ks*32);
  }
  // ---- epilogue constants ----
  float bi[4], wpe[4], wpg[4];
  #pragma unroll
  for(int fc=0;fc<4;fc++){
    int cc = wc*64 + fc*16 + t;
    bi[fc]=bint[cc]; wpe[fc]=Wpe[cc]; wpg[fc]=Wpg[cc];
  }
  const float bpe0 = bpe[0], bpg0 = bpg[0];
  const float* tokn = tok + (size_t)(n*128 + jg*8)*128 + q*8;

  #pragma unroll
  for(int j=0;j<8;j++){
    // pack this j's tok factors for this lane's k positions: 4 half2 per ks
    int tpk[4][4];
    { const float* tr = tokn + j*128;
      #pragma unroll
      for(int ks=0;ks<4;ks++){
        float4v t0 = *(const float4v*)(tr + ks*32);
        float4v t1 = *(const float4v*)(tr + ks*32 + 4);
        tpk[ks][0] = __builtin_bit_cast(int, __builtin_amdgcn_cvt_pkrtz(t0[0],t0[1]));
        tpk[ks][1] = __builtin_bit_cast(int, __builtin_amdgcn_cvt_pkrtz(t0[2],t0[3]));
        tpk[ks][2] = __builtin_bit_cast(int, __builtin_amdgcn_cvt_pkrtz(t1[0],t1[1]));
        tpk[ks][3] = __builtin_bit_cast(int, __builtin_amdgcn_cvt_pkrtz(t1[2],t1[3]));
      }
    }
    float4v acc[2][4];
    #pragma unroll
    for(int fr=0;fr<2;fr++)
      #pragma unroll
      for(int fc=0;fc<4;fc++)
        acc[fr][fc] = (float4v){bi[fc],bi[fc],bi[fc],bi[fc]};
    #pragma unroll
    for(int ks=0;ks<4;ks++){
      half8v s0 = scale_frag16(areg[0][ks], tpk[ks]);
      half8v s1 = scale_frag16(areg[1][ks], tpk[ks]);
      #pragma unroll
      for(int fc=0;fc<4;fc++){
        acc[0][fc] = __builtin_amdgcn_mfma_f32_16x16x32_f16(s0, breg[fc][ks], acc[0][fc], 0,0,0);
        acc[1][fc] = __builtin_amdgcn_mfma_f32_16x16x32_f16(s1, breg[fc][ks], acc[1][fc], 0,0,0);
      }
    }
    // epilogue: rows atom = g*32 + fr*16 + q*4 + r ; cols c in this wave's half
    #pragma unroll
    for(int fr=0;fr<2;fr++){
      #pragma unroll
      for(int r=0;r<4;r++){
        float d1=0.f, d2=0.f;
        #pragma unroll
        for(int fc=0;fc<4;fc++){
          float h = lrelu(acc[fr][fc][r]);
          d1 = fmaf(h, wpe[fc], d1);
          d2 = fmaf(h, wpg[fc], d2);
        }
        d1 = row16_reduce(d1);
        d2 = row16_reduce(d2);
        if(t==0){
          int a = fr*16 + q*4 + r;
          red[j][g][wc][a][0] = d1;
          red[j][g][wc][a][1] = d2;
        }
      }
    }
  }
  __syncthreads();
  if(tid < 64){
    const int gg = tid >> 5, a = tid & 31;
    float s_ = 0.f;
    #pragma unroll
    for(int j=0;j<8;j++){
      float d1 = red[j][gg][0][a][0] + red[j][gg][1][a][0];
      float d2 = red[j][gg][0][a][1] + red[j][gg][1][a][1];
      s_ += (d1 + bpe0) * sigm(d2 + bpg0);
    }
    atomicAdd(atom_e + rbase + tid, s_);
  }
}

// ---------- K_bias_seg: bias head + fused segment-sum (256 thr, split chains) ----------
__global__ __launch_bounds__(256) void k_bias_seg(
    const float* __restrict__ lg, const float* __restrict__ Wg,
    const float* __restrict__ bg, const float* __restrict__ pf,
    const float* __restrict__ W1, const float* __restrict__ b1,
    const float* __restrict__ W2, const float* __restrict__ b2,
    const float* __restrict__ atom_e, const int* __restrict__ batch,
    float* __restrict__ out){
  __shared__ float row[64];
  __shared__ float z[256];
  __shared__ float partA[128];
  __shared__ float partB[128];
  __shared__ float wred[4];
  const int b = blockIdx.x;       // n*64 + g
  const int n = b >> 6, g = b & 63;
  const int tid = threadIdx.x;    // 0..255
  const int c = tid & 127, s = tid >> 7;
  if(tid < 64) row[tid] = lg[b*64 + tid];
  __syncthreads();
  float gf = 0.f;
  #pragma unroll 8
  for(int k=s*32;k<s*32+32;k++) gf = fmaf(row[k], Wg[k*128+c], gf);
  if(s==1) partA[c] = gf;
  __syncthreads();
  if(s==0){ z[c] = pf[n*128+c]; z[128+c] = gf + partA[c] + bg[c]; }
  __syncthreads();
  float tacc = 0.f;
  for(int qq=s*128; qq<s*128+128; qq++) tacc = fmaf(z[qq], W1[qq*128+c], tacc);
  if(s==1) partB[c] = tacc;
  float se = 0.f;
  const float* ae = atom_e + n*1024;
  for(int i=tid;i<1024;i+=256){ float v = ae[i]; se += (batch[i]==g) ? v : 0.f; }
  __syncthreads();
  float val = se;
  if(s==0){
    float tf = lrelu(tacc + partB[c] + b1[c]);
    val += tf * W2[c];
  }
  #pragma unroll
  for(int m=32;m>=1;m>>=1) val += __shfl_xor(val,m);
  if((tid&63)==0) wred[tid>>6] = val;
  __syncthreads();
  if(tid==0) out[b] = wred[0]+wred[1]+wred[2]+wred[3] + b2[0];
}

extern "C" void kernel_launch(void* const* d_in, const int* in_sizes, int n_in,
                              void* d_out, int out_size, void* d_ws, size_t ws_size,
                              hipStream_t stream) {
  const float* ms0   = (const float*)d_in[0];
  const float* ms1   = (const float*)d_in[1];
  const float* tfeat = (const float*)d_in[2];
  const float* la    = (const float*)d_in[3];
  const float* lg    = (const float*)d_in[4];
  const int*   batch = (const int*)  d_in[5];
  const float* Wtok  = (const float*)d_in[6];
  const float* btok  = (const float*)d_in[7];
  const float* Wc0   = (const float*)d_in[8];
  const float* bc0   = (const float*)d_in[9];
  const float* Wc1   = (const float*)d_in[10];
  const float* bc1   = (const float*)d_in[11];
  const float* Wp    = (const float*)d_in[12];
  const float* bp    = (const float*)d_in[13];
  const float* Wcat  = (const float*)d_in[14];
  const float* bcat  = (const float*)d_in[15];
  const float* Wgate = (const float*)d_in[16];
  const float* bgate = (const float*)d_in[17];
  const float* Wa    = (const float*)d_in[18];
  const float* ba    = (const float*)d_in[19];
  const float* Wgr   = (const float*)d_in[20];
  const float* bgr   = (const float*)d_in[21];
  const float* W1    = (const float*)d_in[22];
  const float* b1    = (const float*)d_in[23];
  const float* W2    = (const float*)d_in[24];
  const float* b2    = (const float*)d_in[25];
  const float* Wint  = (const float*)d_in[26];
  const float* bint  = (const float*)d_in[27];
  const float* Wpe   = (const float*)d_in[28];
  const float* bpe   = (const float*)d_in[29];
  const float* Wpg   = (const float*)d_in[30];
  const float* bpg   = (const float*)d_in[31];
  float* out = (float*)d_out;

  float* ws      = (float*)d_ws;
  float* tok     = ws;                         // 65536 f32
  float* S1      = ws + 65536;                 // 6912
  float* S0      = S1 + 6912;                  // 3456
  float* pp      = S0 + 3456;                  // 1024
  float* pf      = pp + 1024;                  // 512
  float* toksum  = pf + 512;                   // 512
  float* atom_e  = toksum + 512;               // 4096
  unsigned short* atoms_h = (unsigned short*)(atom_e + 4096);    // 524288 u16
  unsigned short* Wt      = atoms_h + 524288;                    // 16384 u16

  k_pre<<<3008, 256, 0, stream>>>(tfeat, Wtok, btok, tok,
                                  ms1, S1, ms0, S0,
                                  la, Wa, ba, atoms_h, atom_e,
                                  Wint, Wt);
  k_inter<<<1024, 256, 0, stream>>>(atoms_h, tok, Wt, bint,
                                    Wpe, bpe, Wpg, bpg, atom_e);
  k_pconv<<<NIMG*128, 256, 0, stream>>>(S1, S0, Wc0, bc0, Wc1, bc1,
                                        tok, toksum, pp);
  k_pf2<<<NIMG, 512, 0, stream>>>(pp, toksum, Wp, bp, Wcat, bcat, Wgate, bgate, pf);
  k_bias_seg<<<NIMG*64, 256, 0, stream>>>(lg, Wgr, bgr, pf, W1, b1, W2, b2,
                                          atom_e, batch, out);
}

// Round 9
// 232.907 us; speedup vs baseline: 1.0102x; 1.0102x over previous
//
#include <hip/hip_runtime.h>
#include <hip/hip_bf16.h>

#define NIMG 4

typedef __attribute__((ext_vector_type(8))) _Float16 half8v;
typedef __attribute__((ext_vector_type(4))) float float4v;

__device__ __forceinline__ float sigm(float x){ return 1.f/(1.f+__expf(-x)); }
__device__ __forceinline__ float silu(float x){ return x/(1.f+__expf(-x)); }
__device__ __forceinline__ float lrelu(float x){ return fmaxf(x, 0.01f*x); }

// DPP rotate-add within a 16-lane row (ctrl immediate via template)
template<int CTRL>
__device__ __forceinline__ float dpp_radd(float v){
  int s = __builtin_amdgcn_update_dpp(0, __builtin_bit_cast(int, v), CTRL, 0xF, 0xF, true);
  return v + __builtin_bit_cast(float, s);
}
__device__ __forceinline__ float row16_reduce(float v){
  v = dpp_radd<0x128>(v);  // row_ror:8
  v = dpp_radd<0x124>(v);  // row_ror:4
  v = dpp_radd<0x122>(v);  // row_ror:2
  v = dpp_radd<0x121>(v);  // row_ror:1
  return v;
}

// ---------- windowed-sum device helper ----------
template<int DIM, int ODIM>
__device__ void wsum_body(const float* __restrict__ x, float* __restrict__ S,
                          int vb, float* sh){
  const float* xp = x + (size_t)vb*(DIM*DIM*DIM);
  for(int p=threadIdx.x; p<DIM*DIM*DIM; p+=256) sh[p] = silu(xp[p]);
  __syncthreads();
  const int wave = threadIdx.x>>6, lane = threadIdx.x&63;
  for(int tap=wave; tap<27; tap+=4){
    const int kd=tap/9, kh=(tap/3)%3, kw=tap%3;
    const int base = kd*DIM*DIM + kh*DIM + kw;
    float ps = 0.f;
    for(int idx=lane; idx<ODIM*ODIM*ODIM; idx+=64){
      int od = idx/(ODIM*ODIM); int r = idx - od*(ODIM*ODIM);
      int oh = r/ODIM; int ow = r - oh*ODIM;
      ps += sh[base + od*DIM*DIM + oh*DIM + ow];
    }
    #pragma unroll
    for(int m=32;m>=1;m>>=1) ps += __shfl_xor(ps,m);
    if(lane==0) S[vb*27 + tap] = ps;
  }
}

// ---------- K_pre: fused preprocessing (tok | wsum1 | wsum0 | atoms | wt) ----------
__global__ __launch_bounds__(256) void k_pre(
    const float* __restrict__ tf, const float* __restrict__ Wtok,
    const float* __restrict__ btok, float* __restrict__ tok,
    unsigned short* __restrict__ tok_h,
    const float* __restrict__ ms1, float* __restrict__ S1,
    const float* __restrict__ ms0, float* __restrict__ S0,
    const float* __restrict__ la, const float* __restrict__ Wa,
    const float* __restrict__ ba, unsigned short* __restrict__ atoms_h,
    float* __restrict__ atom_e,
    const float* __restrict__ Wint, unsigned short* __restrict__ Wt){
  __shared__ float sh[4096];
  const int b = blockIdx.x;
  const int tid = threadIdx.x;
  if(b < 512){
    // ---- tok (f32 + fp16 copies) ----
    const int row = b;
    sh[tid] = silu(tf[row*256 + tid]);
    __syncthreads();
    const int c = tid & 127, sg = tid >> 7;
    float acc = 0.f;
    #pragma unroll 8
    for(int q=sg*128; q<sg*128+128; q++) acc = fmaf(sh[q], Wtok[q*128+c], acc);
    if(sg==1) sh[256+c] = acc;
    __syncthreads();
    if(sg==0){
      float v = acc + sh[256+c] + btok[c];
      tok[row*128+c] = v;
      tok_h[row*128+c] = __builtin_bit_cast(unsigned short, (_Float16)v);
    }
  } else if(b < 768){
    wsum_body<8,6>(ms1, S1, b-512, sh);
  } else if(b < 896){
    wsum_body<16,14>(ms0, S0, b-768, sh);
  } else if(b < 2944){
    // ---- atoms (fp16): 2 rows per block ----
    const int rowb = (b-896)*2;
    if(tid < 128) sh[tid] = la[(size_t)rowb*64 + tid];
    __syncthreads();
    const int r2 = tid>>7, c = tid&127;
    const float* s = sh + r2*64;
    float acc = ba[c];
    #pragma unroll 8
    for(int k=0;k<64;k++) acc = fmaf(s[k], Wa[k*128+c], acc);
    atoms_h[(size_t)(rowb+r2)*128 + c] = __builtin_bit_cast(unsigned short, (_Float16)acc);
    if(tid<2) atom_e[rowb+tid] = 0.f;
  } else {
    // ---- Wt[c][k] = fp16(Wint[k][c]) ----
    const int idx = (b-2944)*256 + tid;
    const int c = idx >> 7, k = idx & 127;
    Wt[c*128 + k] = __builtin_bit_cast(unsigned short, (_Float16)(Wint[k*128 + c]));
  }
}

// ---------- K_pconv: per-(n,c) conv dots + toksum ----------
__global__ void k_pconv(const float* __restrict__ S1, const float* __restrict__ S0,
                        const float* __restrict__ Wc0, const float* __restrict__ bc0,
                        const float* __restrict__ Wc1, const float* __restrict__ bc1,
                        const float* __restrict__ tok, float* __restrict__ toksum,
                        float* __restrict__ pp){
  const int b = blockIdx.x;        // n*128 + c
  const int n = b >> 7, c = b & 127;
  const int tid = threadIdx.x;     // 0..255
  float a0 = 0.f, a1 = 0.f, ts = 0.f;
  { const float* w = Wc0 + c*1728; const float* s = S1 + n*1728;
    for(int q=tid; q<1728; q+=256) a0 = fmaf(w[q], s[q], a0); }
  { const float* w = Wc1 + c*864;  const float* s = S0 + n*864;
    for(int q=tid; q<864; q+=256)  a1 = fmaf(w[q], s[q], a1); }
  for(int j=tid; j<128; j+=256) ts = tok[(n*128+j)*128 + c];
  #pragma unroll
  for(int m=32;m>=1;m>>=1){
    a0 += __shfl_xor(a0,m); a1 += __shfl_xor(a1,m); ts += __shfl_xor(ts,m);
  }
  __shared__ float r0[4], r1[4], r2[4];
  if((tid&63)==0){ r0[tid>>6]=a0; r1[tid>>6]=a1; r2[tid>>6]=ts; }
  __syncthreads();
  if(tid==0){
    float p0 = bc0[c] + (r0[0]+r0[1]+r0[2]+r0[3])*(1.f/216.f);
    float p1 = bc1[c] + (r1[0]+r1[1]+r1[2]+r1[3])*(1.f/2744.f);
    pp[n*256 + c]       = silu(p0);
    pp[n*256 + 128 + c] = silu(p1);
    toksum[n*128 + c]   = r2[0]+r2[1]+r2[2]+r2[3];
  }
}

// ---------- K_pock: pocket layer, per-(n,c) 256-dot ----------
__global__ __launch_bounds__(256) void k_pock(
    const float* __restrict__ pp, const float* __restrict__ Wp,
    const float* __restrict__ bp, float* __restrict__ pocket){
  const int b = blockIdx.x;        // n*128 + c
  const int n = b >> 7, c = b & 127;
  const int tid = threadIdx.x;     // 0..255
  float a = pp[n*256 + tid] * Wp[tid*128 + c];
  #pragma unroll
  for(int m=32;m>=1;m>>=1) a += __shfl_xor(a,m);
  __shared__ float r[4];
  if((tid&63)==0) r[tid>>6] = a;
  __syncthreads();
  if(tid==0) pocket[n*128+c] = bp[c] + r[0]+r[1]+r[2]+r[3];
}

// ---------- K_gate: cat/gate layer, per-(n,c) 384-dots ----------
__global__ __launch_bounds__(256) void k_gate(
    const float* __restrict__ pocket, const float* __restrict__ toksum,
    const float* __restrict__ Wcat, const float* __restrict__ bcat,
    const float* __restrict__ Wgate, const float* __restrict__ bgate,
    float* __restrict__ pf){
  __shared__ float zz[384];
  __shared__ float r1s[4], r2s[4];
  const int b = blockIdx.x;        // n*128 + c
  const int n = b >> 7, c = b & 127;
  const int tid = threadIdx.x;     // 0..255
  if(tid < 128){
    float ts = toksum[n*128 + tid];
    zz[tid] = pocket[n*128 + tid];
    zz[128 + tid] = ts;
    zz[256 + tid] = ts*(1.f/128.f);
  }
  __syncthreads();
  float a1 = 0.f, a2 = 0.f;
  for(int q=tid; q<384; q+=256){
    float z = zz[q];
    a1 = fmaf(z, Wcat[q*128+c], a1);
    a2 = fmaf(z, Wgate[q*128+c], a2);
  }
  #pragma unroll
  for(int m=32;m>=1;m>>=1){ a1 += __shfl_xor(a1,m); a2 += __shfl_xor(a2,m); }
  if((tid&63)==0){ r1s[tid>>6]=a1; r2s[tid>>6]=a2; }
  __syncthreads();
  if(tid==0){
    float v1 = bcat[c] + r1s[0]+r1s[1]+r1s[2]+r1s[3];
    float v2 = bgate[c]+ r2s[0]+r2s[1]+r2s[2]+r2s[3];
    pf[n*128+c] = v1 * sigm(v2);
  }
}

// ---------- K_inter v3: fp16 MFMA, fr=1 tiles, 3 waves/SIMD, rolled j-loop ----------
// 256 thr = 4 waves. Wave w: atom-group g=w>>1 (16 atoms), c-half wc=w&1 (64 c).
// Block: 32 atoms x 8 j. Grid: 4n x 32chunk x 16jg = 2048.
// Per j: tok_h fp16 frags loaded direct -> v_pk_mul scale of A -> 16 MFMA vs
// register-resident W^T -> lrelu+dot epilogue, DPP row-reduce -> red[j] (LDS).
// One barrier at end; 32-thread tail combines j & c-halves; 1 atomic per atom.
__global__ __launch_bounds__(256,3) void k_inter(
    const unsigned short* __restrict__ atoms_h,   // [4096][128] fp16
    const unsigned short* __restrict__ tok_h,     // [512][128] fp16
    const unsigned short* __restrict__ Wt,        // [128 c][128 k] fp16
    const float* __restrict__ bint,
    const float* __restrict__ Wpe, const float* __restrict__ bpe,
    const float* __restrict__ Wpg, const float* __restrict__ bpg,
    float* __restrict__ atom_e){
  __shared__ float red[8][2][2][16][2];           // [j][g][wc][row][d] = 4KB

  const int b0 = blockIdx.x;
  const int bid = (b0 & 7)*256 + (b0 >> 3);       // XCD swizzle (2048%8==0)
  const int n = bid >> 9;
  const int chunk = (bid >> 4) & 31;
  const int jg = bid & 15;                        // j base = jg*8
  const int tid = threadIdx.x;
  const int w = tid >> 6, lane = tid & 63;
  const int t = lane & 15, q = lane >> 4;
  const int g = w >> 1, wc = w & 1;

  const int rbase = n*1024 + chunk*32;

  // ---- A fragments (fp16, unscaled): row = rbase+g*16+t, k = ks*32+q*8 ----
  half8v areg[4];
  { const unsigned short* ab = atoms_h + (size_t)(rbase + g*16 + t)*128 + q*8;
    #pragma unroll
    for(int ks=0;ks<4;ks++) areg[ks] = *(const half8v*)(ab + ks*32);
  }
  // ---- B fragments (W^T fp16, j-invariant): c = wc*64+fc*16+t ----
  half8v breg[4][4];
  { const unsigned short* wb = Wt + (size_t)(wc*64 + t)*128 + q*8;
    #pragma unroll
    for(int fc=0;fc<4;fc++)
      #pragma unroll
      for(int ks=0;ks<4;ks++)
        breg[fc][ks] = *(const half8v*)(wb + fc*16*128 + ks*32);
  }
  // ---- epilogue constants ----
  float bi[4], wpe[4], wpg[4];
  #pragma unroll
  for(int fc=0;fc<4;fc++){
    int cc = wc*64 + fc*16 + t;
    bi[fc]=bint[cc]; wpe[fc]=Wpe[cc]; wpg[fc]=Wpg[cc];
  }
  const unsigned short* tokh = tok_h + (size_t)(n*128 + jg*8)*128 + q*8;

  #pragma unroll 2
  for(int j=0;j<8;j++){
    half8v th[4];
    #pragma unroll
    for(int ks=0;ks<4;ks++) th[ks] = *(const half8v*)(tokh + j*128 + ks*32);
    float4v acc[4];
    #pragma unroll
    for(int fc=0;fc<4;fc++) acc[fc] = (float4v){bi[fc],bi[fc],bi[fc],bi[fc]};
    #pragma unroll
    for(int ks=0;ks<4;ks++){
      half8v s = areg[ks] * th[ks];       // v_pk_mul_f16 x4
      #pragma unroll
      for(int fc=0;fc<4;fc++)
        acc[fc] = __builtin_amdgcn_mfma_f32_16x16x32_f16(s, breg[fc][ks], acc[fc], 0,0,0);
    }
    // epilogue: D row = q*4+r -> atom g*16+q*4+r ; col t -> c in wave's half
    #pragma unroll
    for(int r=0;r<4;r++){
      float d1=0.f, d2=0.f;
      #pragma unroll
      for(int fc=0;fc<4;fc++){
        float h = lrelu(acc[fc][r]);
        d1 = fmaf(h, wpe[fc], d1);
        d2 = fmaf(h, wpg[fc], d2);
      }
      d1 = row16_reduce(d1);
      d2 = row16_reduce(d2);
      if(t==0){
        red[j][g][wc][q*4+r][0] = d1;
        red[j][g][wc][q*4+r][1] = d2;
      }
    }
  }
  __syncthreads();
  if(tid < 32){
    const int gg = tid >> 4, a = tid & 15;
    const float bpe0 = bpe[0], bpg0 = bpg[0];
    float s_ = 0.f;
    #pragma unroll
    for(int j=0;j<8;j++){
      float d1 = red[j][gg][0][a][0] + red[j][gg][1][a][0];
      float d2 = red[j][gg][0][a][1] + red[j][gg][1][a][1];
      s_ += (d1 + bpe0) * sigm(d2 + bpg0);
    }
    atomicAdd(atom_e + rbase + tid, s_);
  }
}

// ---------- K_bias_seg: bias head + fused segment-sum ----------
__global__ __launch_bounds__(256) void k_bias_seg(
    const float* __restrict__ lg, const float* __restrict__ Wg,
    const float* __restrict__ bg, const float* __restrict__ pf,
    const float* __restrict__ W1, const float* __restrict__ b1,
    const float* __restrict__ W2, const float* __restrict__ b2,
    const float* __restrict__ atom_e, const int* __restrict__ batch,
    float* __restrict__ out){
  __shared__ float row[64];
  __shared__ float z[256];
  __shared__ float partA[128];
  __shared__ float partB[128];
  __shared__ float wred[4];
  const int b = blockIdx.x;       // n*64 + g
  const int n = b >> 6, g = b & 63;
  const int tid = threadIdx.x;    // 0..255
  const int c = tid & 127, s = tid >> 7;
  if(tid < 64) row[tid] = lg[b*64 + tid];
  __syncthreads();
  float gf = 0.f;
  #pragma unroll 8
  for(int k=s*32;k<s*32+32;k++) gf = fmaf(row[k], Wg[k*128+c], gf);
  if(s==1) partA[c] = gf;
  __syncthreads();
  if(s==0){ z[c] = pf[n*128+c]; z[128+c] = gf + partA[c] + bg[c]; }
  __syncthreads();
  float tacc = 0.f;
  for(int qq=s*128; qq<s*128+128; qq++) tacc = fmaf(z[qq], W1[qq*128+c], tacc);
  if(s==1) partB[c] = tacc;
  float se = 0.f;
  const float* ae = atom_e + n*1024;
  for(int i=tid;i<1024;i+=256){ float v = ae[i]; se += (batch[i]==g) ? v : 0.f; }
  __syncthreads();
  float val = se;
  if(s==0){
    float tf = lrelu(tacc + partB[c] + b1[c]);
    val += tf * W2[c];
  }
  #pragma unroll
  for(int m=32;m>=1;m>>=1) val += __shfl_xor(val,m);
  if((tid&63)==0) wred[tid>>6] = val;
  __syncthreads();
  if(tid==0) out[b] = wred[0]+wred[1]+wred[2]+wred[3] + b2[0];
}

extern "C" void kernel_launch(void* const* d_in, const int* in_sizes, int n_in,
                              void* d_out, int out_size, void* d_ws, size_t ws_size,
                              hipStream_t stream) {
  const float* ms0   = (const float*)d_in[0];
  const float* ms1   = (const float*)d_in[1];
  const float* tfeat = (const float*)d_in[2];
  const float* la    = (const float*)d_in[3];
  const float* lg    = (const float*)d_in[4];
  const int*   batch = (const int*)  d_in[5];
  const float* Wtok  = (const float*)d_in[6];
  const float* btok  = (const float*)d_in[7];
  const float* Wc0   = (const float*)d_in[8];
  const float* bc0   = (const float*)d_in[9];
  const float* Wc1   = (const float*)d_in[10];
  const float* bc1   = (const float*)d_in[11];
  const float* Wp    = (const float*)d_in[12];
  const float* bp    = (const float*)d_in[13];
  const float* Wcat  = (const float*)d_in[14];
  const float* bcat  = (const float*)d_in[15];
  const float* Wgate = (const float*)d_in[16];
  const float* bgate = (const float*)d_in[17];
  const float* Wa    = (const float*)d_in[18];
  const float* ba    = (const float*)d_in[19];
  const float* Wgr   = (const float*)d_in[20];
  const float* bgr   = (const float*)d_in[21];
  const float* W1    = (const float*)d_in[22];
  const float* b1    = (const float*)d_in[23];
  const float* W2    = (const float*)d_in[24];
  const float* b2    = (const float*)d_in[25];
  const float* Wint  = (const float*)d_in[26];
  const float* bint  = (const float*)d_in[27];
  const float* Wpe   = (const float*)d_in[28];
  const float* bpe   = (const float*)d_in[29];
  const float* Wpg   = (const float*)d_in[30];
  const float* bpg   = (const float*)d_in[31];
  float* out = (float*)d_out;

  float* ws      = (float*)d_ws;
  float* tok     = ws;                         // 65536 f32
  float* S1      = ws + 65536;                 // 6912
  float* S0      = S1 + 6912;                  // 3456
  float* pp      = S0 + 3456;                  // 1024
  float* pf      = pp + 1024;                  // 512
  float* toksum  = pf + 512;                   // 512
  float* pocket  = toksum + 512;               // 512
  float* atom_e  = pocket + 512;               // 4096
  unsigned short* atoms_h = (unsigned short*)(atom_e + 4096);    // 524288 u16
  unsigned short* Wt      = atoms_h + 524288;                    // 16384 u16
  unsigned short* tok_h   = Wt + 16384;                          // 65536 u16

  k_pre<<<3008, 256, 0, stream>>>(tfeat, Wtok, btok, tok, tok_h,
                                  ms1, S1, ms0, S0,
                                  la, Wa, ba, atoms_h, atom_e,
                                  Wint, Wt);
  k_inter<<<2048, 256, 0, stream>>>(atoms_h, tok_h, Wt, bint,
                                    Wpe, bpe, Wpg, bpg, atom_e);
  k_pconv<<<NIMG*128, 256, 0, stream>>>(S1, S0, Wc0, bc0, Wc1, bc1,
                                        tok, toksum, pp);
  k_pock<<<NIMG*128, 256, 0, stream>>>(pp, Wp, bp, pocket);
  k_gate<<<NIMG*128, 256, 0, stream>>>(pocket, toksum, Wcat, bcat, Wgate, bgate, pf);
  k_bias_seg<<<NIMG*64, 256, 0, stream>>>(lg, Wgr, bgr, pf, W1, b1, W2, b2,
                                          atom_e, batch, out);
}